// Round 1
// baseline (1516.982 us; speedup 1.0000x reference)
//
#include <hip/hip_runtime.h>
#include <math.h>

#define CH 192
#define HW 4096
#define NB 16
#define NELEM (NB*CH*HW)
#define HIDN 768

__device__ __forceinline__ float gelu_f(float v){
    return 0.5f * v * (1.0f + erff(v * 0.70710678118654752440f));
}
__device__ __forceinline__ float sigmoid_f(float v){
    return 1.0f / (1.0f + expf(-v));
}

// ---------------- K1: LN1 + in_proj (192 -> 384), split into proj / sigmoid(gate)
__global__ __launch_bounds__(256) void k_ln_inproj(
    const float* __restrict__ x, const float* __restrict__ lw, const float* __restrict__ lb,
    const float* __restrict__ W, const float* __restrict__ bias,
    float* __restrict__ proj, float* __restrict__ gate)
{
    __shared__ float xs[CH*64];
    __shared__ float redS[256], redQ[256];
    __shared__ float mS[64], rS[64];
    int tid = threadIdx.x;
    int t = blockIdx.x;
    int b = t >> 6;
    int p0 = (t & 63) << 6;
    const float* xb = x + (size_t)b*CH*HW + p0;
    for (int i = tid; i < CH*64; i += 256){
        int c = i >> 6, p = i & 63;
        xs[i] = xb[(size_t)c*HW + p];
    }
    __syncthreads();
    int pos = tid & 63, q = tid >> 6;
    float s = 0.f, s2 = 0.f;
    for (int c = q*48; c < q*48+48; ++c){
        float v = xs[c*64 + pos];
        s += v; s2 += v*v;
    }
    redS[tid] = s; redQ[tid] = s2;
    __syncthreads();
    if (tid < 64){
        float S = redS[tid]+redS[tid+64]+redS[tid+128]+redS[tid+192];
        float Q = redQ[tid]+redQ[tid+64]+redQ[tid+128]+redQ[tid+192];
        float mean = S * (1.f/192.f);
        float var  = Q * (1.f/192.f) - mean*mean;
        mS[tid] = mean;
        rS[tid] = rsqrtf(var + 1e-6f);
    }
    __syncthreads();
    for (int i = tid; i < CH*64; i += 256){
        int c = i >> 6, p = i & 63;
        xs[i] = (xs[i] - mS[p]) * rS[p] * lw[c] + lb[c];
    }
    __syncthreads();
    int og = __builtin_amdgcn_readfirstlane(q);   // wave-uniform -> scalar weight loads
    for (int ch = 0; ch < 12; ++ch){
        int ocb = og*96 + ch*8;
        float acc[8];
        #pragma unroll
        for (int j = 0; j < 8; ++j) acc[j] = 0.f;
        const float* Wp = W + (size_t)ocb*CH;
        #pragma unroll 8
        for (int c = 0; c < CH; ++c){
            float xv = xs[c*64 + pos];
            #pragma unroll
            for (int j = 0; j < 8; ++j)
                acc[j] = fmaf(xv, Wp[j*CH + c], acc[j]);
        }
        #pragma unroll
        for (int j = 0; j < 8; ++j){
            int oc = ocb + j;
            float v = acc[j] + bias[oc];
            if (oc < CH){
                proj[(size_t)(b*CH + oc)*HW + p0 + pos] = v;
            } else {
                gate[(size_t)(b*CH + (oc-CH))*HW + p0 + pos] = sigmoid_f(v);
            }
        }
    }
}

// ---------------- K2: depthwise 3x3 SAME (cross-correlation)
__global__ __launch_bounds__(256) void k_dwconv(
    const float* __restrict__ in, const float* __restrict__ k9, float* __restrict__ out)
{
    __shared__ float t[66*66];
    int tid = threadIdx.x;
    int bc = blockIdx.x;
    int c = bc % CH;
    for (int i = tid; i < 66*66; i += 256) t[i] = 0.f;
    __syncthreads();
    const float* inp = in + (size_t)bc*HW;
    for (int i = tid; i < HW; i += 256){
        int y = i >> 6, xq = i & 63;
        t[(y+1)*66 + xq + 1] = inp[i];
    }
    __syncthreads();
    float kk[9];
    #pragma unroll
    for (int j = 0; j < 9; ++j) kk[j] = k9[c*9 + j];
    float* op = out + (size_t)bc*HW;
    for (int i = tid; i < HW; i += 256){
        int y = i >> 6, xq = i & 63;
        float sv = 0.f;
        #pragma unroll
        for (int dy = 0; dy < 3; ++dy)
            #pragma unroll
            for (int dx = 0; dx < 3; ++dx)
                sv = fmaf(kk[dy*3+dx], t[(y+dy)*66 + xq + dx], sv);
        op[i] = sv;
    }
}

// ---------------- K3: 4-directional EMA scans + mix, one (b,c) plane per block
__global__ __launch_bounds__(64) void k_scan(
    const float* __restrict__ pc, const float* __restrict__ dl,
    const float* __restrict__ ml, const float* __restrict__ il,
    float* __restrict__ outp)
{
    __shared__ float a[64*65];
    __shared__ float r[64*65];
    int tid = threadIdx.x;
    int bc = blockIdx.x;
    int c = bc % CH;
    float d[4], e[4], m[4], lg[4];
    float mx = -1e30f;
    #pragma unroll
    for (int k = 0; k < 4; ++k){ lg[k] = ml[k*CH + c]; mx = fmaxf(mx, lg[k]); }
    float se = 0.f;
    #pragma unroll
    for (int k = 0; k < 4; ++k){ lg[k] = expf(lg[k]-mx); se += lg[k]; }
    #pragma unroll
    for (int k = 0; k < 4; ++k){
        m[k] = lg[k] / se;
        float dd = sigmoid_f(dl[k*CH + c]);
        dd = fminf(fmaxf(dd, 0.05f), 0.995f);
        d[k] = dd;
        float is = 1.0f + tanhf(il[k*CH + c]);
        e[k] = (1.0f - dd) * is;
    }
    const float* inp = pc + (size_t)bc*HW;
    for (int i = tid; i < HW; i += 64)
        a[(i>>6)*65 + (i&63)] = inp[i];
    __syncthreads();
    {   // horizontal scans: thread = row
        float s = 0.f;
        const int base = tid*65;
        for (int xq = 0; xq < 64; ++xq){
            s = fmaf(d[0], s, e[0]*a[base+xq]);
            r[base+xq] = m[0]*s;
        }
        s = 0.f;
        for (int xq = 63; xq >= 0; --xq){
            s = fmaf(d[1], s, e[1]*a[base+xq]);
            r[base+xq] += m[1]*s;
        }
    }
    __syncthreads();
    {   // vertical scans: thread = column
        float s = 0.f;
        for (int y = 0; y < 64; ++y){
            s = fmaf(d[2], s, e[2]*a[y*65+tid]);
            r[y*65+tid] += m[2]*s;
        }
        s = 0.f;
        for (int y = 63; y >= 0; --y){
            s = fmaf(d[3], s, e[3]*a[y*65+tid]);
            r[y*65+tid] += m[3]*s;
        }
    }
    __syncthreads();
    float* op = outp + (size_t)bc*HW;
    for (int i = tid; i < HW; i += 64)
        op[i] = r[(i>>6)*65 + (i&63)];
}

// ---------------- K4: local 3x3 conv + mix + gate (in-place over gate buf) + BN partial stats
__global__ __launch_bounds__(256) void k_local_mix(
    const float* __restrict__ pc, const float* __restrict__ k9,
    const float* __restrict__ scn, const float* gate,
    float* mixed, float* __restrict__ part)
{
    __shared__ float t[66*66];
    __shared__ float rs[256], rq[256];
    int tid = threadIdx.x;
    int bc = blockIdx.x;
    int c = bc % CH;
    for (int i = tid; i < 66*66; i += 256) t[i] = 0.f;
    __syncthreads();
    const float* inp = pc + (size_t)bc*HW;
    for (int i = tid; i < HW; i += 256){
        int y = i >> 6, xq = i & 63;
        t[(y+1)*66 + xq + 1] = inp[i];
    }
    __syncthreads();
    float kk[9];
    #pragma unroll
    for (int j = 0; j < 9; ++j) kk[j] = k9[c*9 + j];
    float s1 = 0.f, s2 = 0.f;
    const float* sp = scn + (size_t)bc*HW;
    const float* gp = gate + (size_t)bc*HW;
    float* mp = mixed + (size_t)bc*HW;
    for (int i = tid; i < HW; i += 256){
        int y = i >> 6, xq = i & 63;
        float sv = 0.f;
        #pragma unroll
        for (int dy = 0; dy < 3; ++dy)
            #pragma unroll
            for (int dx = 0; dx < 3; ++dx)
                sv = fmaf(kk[dy*3+dx], t[(y+dy)*66 + xq + dx], sv);
        float mv = (sp[i] + sv) * gp[i];
        mp[i] = mv;
        s1 += mv; s2 += mv*mv;
    }
    rs[tid] = s1; rq[tid] = s2;
    __syncthreads();
    for (int off = 128; off > 0; off >>= 1){
        if (tid < off){ rs[tid] += rs[tid+off]; rq[tid] += rq[tid+off]; }
        __syncthreads();
    }
    if (tid == 0){ part[bc] = rs[0]; part[NB*CH + bc] = rq[0]; }
}

// ---------------- K4b: finalize BN scale/shift per channel (deterministic)
__global__ __launch_bounds__(192) void k_bn_final(
    const float* __restrict__ part, const float* __restrict__ bw,
    const float* __restrict__ bb, float* __restrict__ bnp)
{
    int c = threadIdx.x;
    float S = 0.f, Q = 0.f;
    for (int b = 0; b < NB; ++b){
        S += part[b*CH + c];
        Q += part[NB*CH + b*CH + c];
    }
    float mean = S * (1.f/65536.f);
    float var  = Q * (1.f/65536.f) - mean*mean;
    float sc = bw[c] * rsqrtf(var + 1e-5f);
    bnp[c] = sc;
    bnp[CH + c] = bb[c] - mean * sc;
}

// ---------------- K5: BN+GELU transform + out_proj (192->192) + residual -> d_out (xr)
__global__ __launch_bounds__(256) void k_outproj(
    const float* __restrict__ mixed, const float* __restrict__ bnp,
    const float* __restrict__ W, const float* __restrict__ bias,
    const float* __restrict__ x, float* __restrict__ xr)
{
    __shared__ float xs[CH*64];
    int tid = threadIdx.x;
    int t = blockIdx.x;
    int b = t >> 6;
    int p0 = (t & 63) << 6;
    const float* mb = mixed + (size_t)b*CH*HW + p0;
    for (int i = tid; i < CH*64; i += 256){
        int c = i >> 6, p = i & 63;
        float v = mb[(size_t)c*HW + p];
        v = fmaf(v, bnp[c], bnp[CH + c]);
        xs[i] = gelu_f(v);
    }
    __syncthreads();
    int pos = tid & 63;
    int og = __builtin_amdgcn_readfirstlane(tid >> 6);
    for (int ch = 0; ch < 6; ++ch){
        int ocb = og*48 + ch*8;
        float acc[8];
        #pragma unroll
        for (int j = 0; j < 8; ++j) acc[j] = 0.f;
        const float* Wp = W + (size_t)ocb*CH;
        #pragma unroll 8
        for (int c = 0; c < CH; ++c){
            float xv = xs[c*64 + pos];
            #pragma unroll
            for (int j = 0; j < 8; ++j)
                acc[j] = fmaf(xv, Wp[j*CH + c], acc[j]);
        }
        #pragma unroll
        for (int j = 0; j < 8; ++j){
            int oc = ocb + j;
            size_t idx = (size_t)(b*CH + oc)*HW + p0 + pos;
            xr[idx] = x[idx] + bias[oc] + acc[j];
        }
    }
}

// ---------------- K6: LN2 + fc1 + GELU + fc2 + residual, fused (no HID-sized buffer), in-place on d_out
__global__ __launch_bounds__(256) void k_mlp(
    const float* __restrict__ lw, const float* __restrict__ lb,
    const float* __restrict__ W1, const float* __restrict__ b1,
    const float* __restrict__ W2, const float* __restrict__ b2,
    float* io)
{
    __shared__ float h2[CH*64];
    __shared__ float tt[128*64];
    int tid = threadIdx.x;
    int t = blockIdx.x;
    int b = t >> 6;
    int p0 = (t & 63) << 6;
    float* iob = io + (size_t)b*CH*HW + p0;
    for (int i = tid; i < CH*64; i += 256){
        int c = i >> 6, p = i & 63;
        h2[i] = iob[(size_t)c*HW + p];
    }
    __syncthreads();
    int pos = tid & 63, q = tid >> 6;
    float* redS = tt;          // reuse tt as LN scratch before first chunk
    float* redQ = tt + 256;
    float* mS   = tt + 512;
    float* rS   = tt + 576;
    float s = 0.f, s2 = 0.f;
    for (int c = q*48; c < q*48+48; ++c){
        float v = h2[c*64 + pos];
        s += v; s2 += v*v;
    }
    redS[tid] = s; redQ[tid] = s2;
    __syncthreads();
    if (tid < 64){
        float S = redS[tid]+redS[tid+64]+redS[tid+128]+redS[tid+192];
        float Q = redQ[tid]+redQ[tid+64]+redQ[tid+128]+redQ[tid+192];
        float mean = S * (1.f/192.f);
        float var  = Q * (1.f/192.f) - mean*mean;
        mS[tid] = mean;
        rS[tid] = rsqrtf(var + 1e-6f);
    }
    __syncthreads();
    for (int i = tid; i < CH*64; i += 256){
        int c = i >> 6, p = i & 63;
        h2[i] = (h2[i] - mS[p]) * rS[p] * lw[c] + lb[c];
    }
    __syncthreads();
    int og = __builtin_amdgcn_readfirstlane(q);
    float acc[48];
    #pragma unroll
    for (int j = 0; j < 48; ++j) acc[j] = 0.f;
    for (int hc = 0; hc < 6; ++hc){
        for (int jc = 0; jc < 4; ++jc){
            int hrb = og*32 + jc*8;
            float at[8];
            #pragma unroll
            for (int j = 0; j < 8; ++j) at[j] = 0.f;
            const float* W1p = W1 + (size_t)(hc*128 + hrb)*CH;
            #pragma unroll 8
            for (int c = 0; c < CH; ++c){
                float xv = h2[c*64 + pos];
                #pragma unroll
                for (int j = 0; j < 8; ++j)
                    at[j] = fmaf(xv, W1p[j*CH + c], at[j]);
            }
            #pragma unroll
            for (int j = 0; j < 8; ++j){
                int hr = hrb + j;
                tt[hr*64 + pos] = gelu_f(at[j] + b1[hc*128 + hr]);
            }
        }
        __syncthreads();
        #pragma unroll
        for (int oj = 0; oj < 6; ++oj){
            const float* W2p = W2 + (size_t)(og*48 + oj*8)*HIDN + hc*128;
            #pragma unroll 4
            for (int k = 0; k < 128; ++k){
                float tv = tt[k*64 + pos];
                #pragma unroll
                for (int j = 0; j < 8; ++j)
                    acc[oj*8 + j] = fmaf(tv, W2p[j*HIDN + k], acc[oj*8 + j]);
            }
        }
        __syncthreads();
    }
    #pragma unroll
    for (int oj = 0; oj < 6; ++oj){
        #pragma unroll
        for (int j = 0; j < 8; ++j){
            int oc = og*48 + oj*8 + j;
            size_t idx = (size_t)(b*CH + oc)*HW + p0 + pos;
            io[idx] = io[idx] + b2[oc] + acc[oj*8 + j];
        }
    }
}

extern "C" void kernel_launch(void* const* d_in, const int* in_sizes, int n_in,
                              void* d_out, int out_size, void* d_ws, size_t ws_size,
                              hipStream_t stream) {
    const float* x    = (const float*)d_in[0];
    const float* ln1w = (const float*)d_in[1];
    const float* ln1b = (const float*)d_in[2];
    const float* ipw  = (const float*)d_in[3];
    const float* ipb  = (const float*)d_in[4];
    const float* dwk  = (const float*)d_in[5];
    const float* lek  = (const float*)d_in[6];
    const float* dlg  = (const float*)d_in[7];
    const float* mlg  = (const float*)d_in[8];
    const float* isc  = (const float*)d_in[9];
    const float* bnw  = (const float*)d_in[10];
    const float* bnb  = (const float*)d_in[11];
    const float* opw  = (const float*)d_in[12];
    const float* opb  = (const float*)d_in[13];
    const float* ln2w = (const float*)d_in[14];
    const float* ln2b = (const float*)d_in[15];
    const float* f1w  = (const float*)d_in[16];
    const float* f1b  = (const float*)d_in[17];
    const float* f2w  = (const float*)d_in[18];
    const float* f2b  = (const float*)d_in[19];

    float* out  = (float*)d_out;
    float* ws   = (float*)d_ws;
    float* bufA = ws;              // proj, then scanned
    float* bufB = ws + (size_t)NELEM;   // sigmoid(gate), then mixed (in-place)
    float* bufC = ws + (size_t)2*NELEM; // pconv (dwconv'd projected)
    float* part = ws + (size_t)3*NELEM; // 2*3072 BN partials
    float* bnp  = part + 2*NB*CH;       // 2*192 BN scale/shift

    k_ln_inproj<<<1024, 256, 0, stream>>>(x, ln1w, ln1b, ipw, ipb, bufA, bufB);
    k_dwconv  <<<NB*CH, 256, 0, stream>>>(bufA, dwk, bufC);
    k_scan    <<<NB*CH,  64, 0, stream>>>(bufC, dlg, mlg, isc, bufA);
    k_local_mix<<<NB*CH, 256, 0, stream>>>(bufC, lek, bufA, bufB, bufB, part);
    k_bn_final<<<1, 192, 0, stream>>>(part, bnw, bnb, bnp);
    k_outproj <<<1024, 256, 0, stream>>>(bufB, bnp, opw, opb, x, out);
    k_mlp     <<<1024, 256, 0, stream>>>(ln2w, ln2b, f1w, f1b, f2w, f2b, out);
}

// Round 2
// 611.947 us; speedup vs baseline: 2.4789x; 2.4789x over previous
//
#include <hip/hip_runtime.h>
#include <math.h>

#define CH 192
#define HW 4096
#define NB 16
#define NELEM (NB*CH*HW)
#define HIDN 768

typedef __bf16 bf16x8 __attribute__((ext_vector_type(8)));
typedef float  f32x4  __attribute__((ext_vector_type(4)));

__device__ __forceinline__ float gelu_f(float v){
    return 0.5f * v * (1.0f + erff(v * 0.70710678118654752440f));
}
__device__ __forceinline__ float sigmoid_f(float v){
    return 1.0f / (1.0f + expf(-v));
}
__device__ __forceinline__ unsigned short f2bf(float f){
    union { float f; unsigned u; } v; v.f = f;
    unsigned r = (v.u + 0x7FFFu + ((v.u >> 16) & 1u)) >> 16;
    return (unsigned short)r;
}

// ---------------- K0: f32 -> bf16 weight conversion
__global__ __launch_bounds__(256) void k_cvt(const float* __restrict__ a,
                                             unsigned short* __restrict__ o, int n){
    int i = blockIdx.x*256 + threadIdx.x;
    if (i < n) o[i] = f2bf(a[i]);
}

// ---------------- K1: LN1 + in_proj (192 -> 384), split into proj / sigmoid(gate)
__global__ __launch_bounds__(256) void k_ln_inproj(
    const float* __restrict__ x, const float* __restrict__ lw, const float* __restrict__ lb,
    const float* __restrict__ W, const float* __restrict__ bias,
    float* __restrict__ proj, float* __restrict__ gate)
{
    __shared__ float xs[CH*64];
    __shared__ float redS[256], redQ[256];
    __shared__ float mS[64], rS[64];
    int tid = threadIdx.x;
    int t = blockIdx.x;
    int b = t >> 6;
    int p0 = (t & 63) << 6;
    const float* xb = x + (size_t)b*CH*HW + p0;
    for (int i = tid; i < CH*64; i += 256){
        int c = i >> 6, p = i & 63;
        xs[i] = xb[(size_t)c*HW + p];
    }
    __syncthreads();
    int pos = tid & 63, q = tid >> 6;
    float s = 0.f, s2 = 0.f;
    for (int c = q*48; c < q*48+48; ++c){
        float v = xs[c*64 + pos];
        s += v; s2 += v*v;
    }
    redS[tid] = s; redQ[tid] = s2;
    __syncthreads();
    if (tid < 64){
        float S = redS[tid]+redS[tid+64]+redS[tid+128]+redS[tid+192];
        float Q = redQ[tid]+redQ[tid+64]+redQ[tid+128]+redQ[tid+192];
        float mean = S * (1.f/192.f);
        float var  = Q * (1.f/192.f) - mean*mean;
        mS[tid] = mean;
        rS[tid] = rsqrtf(var + 1e-6f);
    }
    __syncthreads();
    for (int i = tid; i < CH*64; i += 256){
        int c = i >> 6, p = i & 63;
        xs[i] = (xs[i] - mS[p]) * rS[p] * lw[c] + lb[c];
    }
    __syncthreads();
    int og = __builtin_amdgcn_readfirstlane(q);   // wave-uniform -> scalar weight loads
    for (int ch = 0; ch < 12; ++ch){
        int ocb = og*96 + ch*8;
        float acc[8];
        #pragma unroll
        for (int j = 0; j < 8; ++j) acc[j] = 0.f;
        const float* Wp = W + (size_t)ocb*CH;
        #pragma unroll 8
        for (int c = 0; c < CH; ++c){
            float xv = xs[c*64 + pos];
            #pragma unroll
            for (int j = 0; j < 8; ++j)
                acc[j] = fmaf(xv, Wp[j*CH + c], acc[j]);
        }
        #pragma unroll
        for (int j = 0; j < 8; ++j){
            int oc = ocb + j;
            float v = acc[j] + bias[oc];
            if (oc < CH){
                proj[(size_t)(b*CH + oc)*HW + p0 + pos] = v;
            } else {
                gate[(size_t)(b*CH + (oc-CH))*HW + p0 + pos] = sigmoid_f(v);
            }
        }
    }
}

// ---------------- K2: depthwise 3x3 SAME (cross-correlation)
__global__ __launch_bounds__(256) void k_dwconv(
    const float* __restrict__ in, const float* __restrict__ k9, float* __restrict__ out)
{
    __shared__ float t[66*66];
    int tid = threadIdx.x;
    int bc = blockIdx.x;
    int c = bc % CH;
    for (int i = tid; i < 66*66; i += 256) t[i] = 0.f;
    __syncthreads();
    const float* inp = in + (size_t)bc*HW;
    for (int i = tid; i < HW; i += 256){
        int y = i >> 6, xq = i & 63;
        t[(y+1)*66 + xq + 1] = inp[i];
    }
    __syncthreads();
    float kk[9];
    #pragma unroll
    for (int j = 0; j < 9; ++j) kk[j] = k9[c*9 + j];
    float* op = out + (size_t)bc*HW;
    for (int i = tid; i < HW; i += 256){
        int y = i >> 6, xq = i & 63;
        float sv = 0.f;
        #pragma unroll
        for (int dy = 0; dy < 3; ++dy)
            #pragma unroll
            for (int dx = 0; dx < 3; ++dx)
                sv = fmaf(kk[dy*3+dx], t[(y+dy)*66 + xq + dx], sv);
        op[i] = sv;
    }
}

// ---------------- K3: 4-directional EMA scans + mix, one (b,c) plane per block
__global__ __launch_bounds__(64) void k_scan(
    const float* __restrict__ pc, const float* __restrict__ dl,
    const float* __restrict__ ml, const float* __restrict__ il,
    float* __restrict__ outp)
{
    __shared__ float a[64*65];
    __shared__ float r[64*65];
    int tid = threadIdx.x;
    int bc = blockIdx.x;
    int c = bc % CH;
    float d[4], e[4], m[4], lg[4];
    float mx = -1e30f;
    #pragma unroll
    for (int k = 0; k < 4; ++k){ lg[k] = ml[k*CH + c]; mx = fmaxf(mx, lg[k]); }
    float se = 0.f;
    #pragma unroll
    for (int k = 0; k < 4; ++k){ lg[k] = expf(lg[k]-mx); se += lg[k]; }
    #pragma unroll
    for (int k = 0; k < 4; ++k){
        m[k] = lg[k] / se;
        float dd = sigmoid_f(dl[k*CH + c]);
        dd = fminf(fmaxf(dd, 0.05f), 0.995f);
        d[k] = dd;
        float is = 1.0f + tanhf(il[k*CH + c]);
        e[k] = (1.0f - dd) * is;
    }
    const float* inp = pc + (size_t)bc*HW;
    for (int i = tid; i < HW; i += 64)
        a[(i>>6)*65 + (i&63)] = inp[i];
    __syncthreads();
    {   // horizontal scans: thread = row
        float s = 0.f;
        const int base = tid*65;
        for (int xq = 0; xq < 64; ++xq){
            s = fmaf(d[0], s, e[0]*a[base+xq]);
            r[base+xq] = m[0]*s;
        }
        s = 0.f;
        for (int xq = 63; xq >= 0; --xq){
            s = fmaf(d[1], s, e[1]*a[base+xq]);
            r[base+xq] += m[1]*s;
        }
    }
    __syncthreads();
    {   // vertical scans: thread = column
        float s = 0.f;
        for (int y = 0; y < 64; ++y){
            s = fmaf(d[2], s, e[2]*a[y*65+tid]);
            r[y*65+tid] += m[2]*s;
        }
        s = 0.f;
        for (int y = 63; y >= 0; --y){
            s = fmaf(d[3], s, e[3]*a[y*65+tid]);
            r[y*65+tid] += m[3]*s;
        }
    }
    __syncthreads();
    float* op = outp + (size_t)bc*HW;
    for (int i = tid; i < HW; i += 64)
        op[i] = r[(i>>6)*65 + (i&63)];
}

// ---------------- K4: local 3x3 conv + mix + gate + BN partial stats
__global__ __launch_bounds__(256) void k_local_mix(
    const float* __restrict__ pc, const float* __restrict__ k9,
    const float* __restrict__ scn, const float* gate,
    float* mixed, float* __restrict__ part)
{
    __shared__ float t[66*66];
    __shared__ float rs[256], rq[256];
    int tid = threadIdx.x;
    int bc = blockIdx.x;
    int c = bc % CH;
    for (int i = tid; i < 66*66; i += 256) t[i] = 0.f;
    __syncthreads();
    const float* inp = pc + (size_t)bc*HW;
    for (int i = tid; i < HW; i += 256){
        int y = i >> 6, xq = i & 63;
        t[(y+1)*66 + xq + 1] = inp[i];
    }
    __syncthreads();
    float kk[9];
    #pragma unroll
    for (int j = 0; j < 9; ++j) kk[j] = k9[c*9 + j];
    float s1 = 0.f, s2 = 0.f;
    const float* sp = scn + (size_t)bc*HW;
    const float* gp = gate + (size_t)bc*HW;
    float* mp = mixed + (size_t)bc*HW;
    for (int i = tid; i < HW; i += 256){
        int y = i >> 6, xq = i & 63;
        float sv = 0.f;
        #pragma unroll
        for (int dy = 0; dy < 3; ++dy)
            #pragma unroll
            for (int dx = 0; dx < 3; ++dx)
                sv = fmaf(kk[dy*3+dx], t[(y+dy)*66 + xq + dx], sv);
        float mv = (sp[i] + sv) * gp[i];
        mp[i] = mv;
        s1 += mv; s2 += mv*mv;
    }
    rs[tid] = s1; rq[tid] = s2;
    __syncthreads();
    for (int off = 128; off > 0; off >>= 1){
        if (tid < off){ rs[tid] += rs[tid+off]; rq[tid] += rq[tid+off]; }
        __syncthreads();
    }
    if (tid == 0){ part[bc] = rs[0]; part[NB*CH + bc] = rq[0]; }
}

// ---------------- K4b: finalize BN scale/shift per channel (deterministic)
__global__ __launch_bounds__(192) void k_bn_final(
    const float* __restrict__ part, const float* __restrict__ bw,
    const float* __restrict__ bb, float* __restrict__ bnp)
{
    int c = threadIdx.x;
    float S = 0.f, Q = 0.f;
    for (int b = 0; b < NB; ++b){
        S += part[b*CH + c];
        Q += part[NB*CH + b*CH + c];
    }
    float mean = S * (1.f/65536.f);
    float var  = Q * (1.f/65536.f) - mean*mean;
    float sc = bw[c] * rsqrtf(var + 1e-5f);
    bnp[c] = sc;
    bnp[CH + c] = bb[c] - mean * sc;
}

// ---------------- K5: BN+GELU transform + out_proj (192->192) + residual -> d_out (xr)
__global__ __launch_bounds__(256) void k_outproj(
    const float* __restrict__ mixed, const float* __restrict__ bnp,
    const float* __restrict__ W, const float* __restrict__ bias,
    const float* __restrict__ x, float* __restrict__ xr)
{
    __shared__ float xs[CH*64];
    int tid = threadIdx.x;
    int t = blockIdx.x;
    int b = t >> 6;
    int p0 = (t & 63) << 6;
    const float* mb = mixed + (size_t)b*CH*HW + p0;
    for (int i = tid; i < CH*64; i += 256){
        int c = i >> 6, p = i & 63;
        float v = mb[(size_t)c*HW + p];
        v = fmaf(v, bnp[c], bnp[CH + c]);
        xs[i] = gelu_f(v);
    }
    __syncthreads();
    int pos = tid & 63;
    int og = __builtin_amdgcn_readfirstlane(tid >> 6);
    for (int ch = 0; ch < 6; ++ch){
        int ocb = og*48 + ch*8;
        float acc[8];
        #pragma unroll
        for (int j = 0; j < 8; ++j) acc[j] = 0.f;
        const float* Wp = W + (size_t)ocb*CH;
        #pragma unroll 8
        for (int c = 0; c < CH; ++c){
            float xv = xs[c*64 + pos];
            #pragma unroll
            for (int j = 0; j < 8; ++j)
                acc[j] = fmaf(xv, Wp[j*CH + c], acc[j]);
        }
        #pragma unroll
        for (int j = 0; j < 8; ++j){
            int oc = ocb + j;
            size_t idx = (size_t)(b*CH + oc)*HW + p0 + pos;
            xr[idx] = x[idx] + bias[oc] + acc[j];
        }
    }
}

// ---------------- K6: LN2 + fc1(bf16 MFMA) + GELU + fc2(bf16 MFMA) + residual, in-place on d_out
// Block = 64 pixels, 4 waves. A-operand = LN2(x)^T staged fragment-linear in LDS.
// Waves partition output channels; weights read once per block from L2-hot bf16 copies.
__global__ __launch_bounds__(256, 2) void k_mlp(
    const float* __restrict__ lw, const float* __restrict__ lb,
    const unsigned short* __restrict__ w1b, const float* __restrict__ b1,
    const unsigned short* __restrict__ w2b, const float* __restrict__ b2,
    float* io)
{
    __shared__ __align__(16) float smemf[12480];   // 49920 B, multi-purpose
    unsigned short* h2s = (unsigned short*)smemf;  // 192*64 bf16 frag-linear (24576 B)
    float* redS = smemf + 6144;
    float* redQ = redS + 256;
    float* mS   = redQ + 256;
    float* rS   = mS + 64;
    unsigned short* tt = (unsigned short*)smemf;   // 128*64 bf16 frag-linear (aliases h2s)
    float* outb = smemf;                           // 192*65 f32 bounce (aliases all)

    int tid = threadIdx.x;
    int lane = tid & 63;
    int w = tid >> 6;
    int lo = lane & 15, hi = lane >> 4;
    int t = blockIdx.x;
    int b = t >> 6;
    int p0 = (t & 63) << 6;
    float* iob = io + (size_t)b*CH*HW + p0;
    int px = lane;      // this thread's pixel for the LN phase (tid&63)

    // ---- load 48 channels for this pixel, LN2 stats
    float xv[48];
    float s = 0.f, s2 = 0.f;
    #pragma unroll
    for (int k = 0; k < 48; ++k){
        float v = iob[(size_t)(w + 4*k)*HW + px];
        xv[k] = v; s += v; s2 += v*v;
    }
    redS[tid] = s; redQ[tid] = s2;
    __syncthreads();
    if (tid < 64){
        float S = redS[tid]+redS[tid+64]+redS[tid+128]+redS[tid+192];
        float Q = redQ[tid]+redQ[tid+64]+redQ[tid+128]+redQ[tid+192];
        float mean = S * (1.f/192.f);
        float var  = Q * (1.f/192.f) - mean*mean;
        mS[tid] = mean;
        rS[tid] = rsqrtf(var + 1e-6f);
    }
    __syncthreads();
    {
        float mean = mS[px], rstd = rS[px];
        #pragma unroll
        for (int k = 0; k < 48; ++k){
            int c = w + 4*k;
            float v = (xv[k] - mean) * rstd * lw[c] + lb[c];
            int ks = c >> 5, hh = (c >> 3) & 3, j2 = c & 7;
            int idx = ((((px >> 4)*6 + ks) << 6) + hh*16 + (px & 15))*8 + j2;
            h2s[idx] = f2bf(v);
        }
    }
    __syncthreads();

    // ---- A fragments (pixels x K) into registers: 4 pt-tiles x 6 k-steps
    bf16x8 afr[4][6];
    #pragma unroll
    for (int pt = 0; pt < 4; ++pt)
        #pragma unroll
        for (int ks = 0; ks < 6; ++ks)
            afr[pt][ks] = *(const bf16x8*)(const void*)(h2s + ((pt*6 + ks)*64 + lane)*8);
    __syncthreads();   // h2s region free for tt now

    f32x4 acc2[3][4];
    #pragma unroll
    for (int nt2 = 0; nt2 < 3; ++nt2)
        #pragma unroll
        for (int pt = 0; pt < 4; ++pt)
            acc2[nt2][pt] = (f32x4){0.f,0.f,0.f,0.f};

    for (int hc = 0; hc < 6; ++hc){
        // fc1: hidden chunk [hc*128, hc*128+128); wave covers rows w*32..w*32+31
        f32x4 acc1[2][4];
        #pragma unroll
        for (int nt = 0; nt < 2; ++nt)
            #pragma unroll
            for (int pt = 0; pt < 4; ++pt)
                acc1[nt][pt] = (f32x4){0.f,0.f,0.f,0.f};
        #pragma unroll
        for (int ks = 0; ks < 6; ++ks){
            #pragma unroll
            for (int nt = 0; nt < 2; ++nt){
                bf16x8 bf = *(const bf16x8*)(const void*)
                    (w1b + (size_t)(hc*128 + w*32 + nt*16 + lo)*CH + ks*32 + hi*8);
                #pragma unroll
                for (int pt = 0; pt < 4; ++pt)
                    acc1[nt][pt] = __builtin_amdgcn_mfma_f32_16x16x32_bf16(
                        afr[pt][ks], bf, acc1[nt][pt], 0, 0, 0);
            }
        }
        // bias + gelu -> tt (frag-linear for fc2's A operand)
        #pragma unroll
        for (int nt = 0; nt < 2; ++nt){
            int hr = w*32 + nt*16 + lo;            // hidden row within chunk [0,128)
            float bias1 = b1[hc*128 + hr];
            int ks2 = hr >> 5, hh = (hr >> 3) & 3, j2 = hr & 7;
            #pragma unroll
            for (int pt = 0; pt < 4; ++pt){
                #pragma unroll
                for (int r = 0; r < 4; ++r){
                    int ppx = pt*16 + hi*4 + r;
                    float v = gelu_f(acc1[nt][pt][r] + bias1);
                    tt[((((ppx >> 4)*4 + ks2) << 6) + hh*16 + (ppx & 15))*8 + j2] = f2bf(v);
                }
            }
        }
        __syncthreads();
        // fc2 partial: wave covers out channels w*48..w*48+47 (3 n-tiles)
        #pragma unroll
        for (int ks2 = 0; ks2 < 4; ++ks2){
            bf16x8 a2[4];
            #pragma unroll
            for (int pt = 0; pt < 4; ++pt)
                a2[pt] = *(const bf16x8*)(const void*)(tt + ((pt*4 + ks2)*64 + lane)*8);
            #pragma unroll
            for (int nt2 = 0; nt2 < 3; ++nt2){
                bf16x8 bf2 = *(const bf16x8*)(const void*)
                    (w2b + (size_t)(w*48 + nt2*16 + lo)*HIDN + hc*128 + ks2*32 + hi*8);
                #pragma unroll
                for (int pt = 0; pt < 4; ++pt)
                    acc2[nt2][pt] = __builtin_amdgcn_mfma_f32_16x16x32_bf16(
                        a2[pt], bf2, acc2[nt2][pt], 0, 0, 0);
            }
        }
        __syncthreads();   // tt free for next chunk
    }

    // ---- epilogue: bounce transposed acc through LDS, coalesced residual store
    #pragma unroll
    for (int nt2 = 0; nt2 < 3; ++nt2){
        int oc = w*48 + nt2*16 + lo;
        #pragma unroll
        for (int pt = 0; pt < 4; ++pt)
            #pragma unroll
            for (int r = 0; r < 4; ++r)
                outb[oc*65 + pt*16 + hi*4 + r] = acc2[nt2][pt][r];
    }
    __syncthreads();
    for (int i = tid; i < CH*64; i += 256){
        int c = i >> 6, p = i & 63;
        size_t idx = (size_t)c*HW + p;
        iob[idx] = iob[idx] + b2[c] + outb[c*65 + p];
    }
}

extern "C" void kernel_launch(void* const* d_in, const int* in_sizes, int n_in,
                              void* d_out, int out_size, void* d_ws, size_t ws_size,
                              hipStream_t stream) {
    const float* x    = (const float*)d_in[0];
    const float* ln1w = (const float*)d_in[1];
    const float* ln1b = (const float*)d_in[2];
    const float* ipw  = (const float*)d_in[3];
    const float* ipb  = (const float*)d_in[4];
    const float* dwk  = (const float*)d_in[5];
    const float* lek  = (const float*)d_in[6];
    const float* dlg  = (const float*)d_in[7];
    const float* mlg  = (const float*)d_in[8];
    const float* isc  = (const float*)d_in[9];
    const float* bnw  = (const float*)d_in[10];
    const float* bnb  = (const float*)d_in[11];
    const float* opw  = (const float*)d_in[12];
    const float* opb  = (const float*)d_in[13];
    const float* ln2w = (const float*)d_in[14];
    const float* ln2b = (const float*)d_in[15];
    const float* f1w  = (const float*)d_in[16];
    const float* f1b  = (const float*)d_in[17];
    const float* f2w  = (const float*)d_in[18];
    const float* f2b  = (const float*)d_in[19];

    float* out  = (float*)d_out;
    float* ws   = (float*)d_ws;
    float* bufA = ws;                    // proj, then scanned, then bf16 weights
    float* bufB = ws + (size_t)NELEM;    // sigmoid(gate), then mixed (in-place)
    float* bufC = ws + (size_t)2*NELEM;  // pconv (dwconv'd projected)
    float* part = ws + (size_t)3*NELEM;  // 2*3072 BN partials
    float* bnp  = part + 2*NB*CH;        // 2*192 BN scale/shift

    unsigned short* w1b = (unsigned short*)bufA;       // after k_local_mix, bufA is free
    unsigned short* w2b = w1b + (size_t)HIDN*CH;

    k_ln_inproj<<<1024, 256, 0, stream>>>(x, ln1w, ln1b, ipw, ipb, bufA, bufB);
    k_dwconv  <<<NB*CH, 256, 0, stream>>>(bufA, dwk, bufC);
    k_scan    <<<NB*CH,  64, 0, stream>>>(bufC, dlg, mlg, isc, bufA);
    k_local_mix<<<NB*CH, 256, 0, stream>>>(bufC, lek, bufA, bufB, bufB, part);
    k_bn_final<<<1, 192, 0, stream>>>(part, bnw, bnb, bnp);
    k_cvt     <<<(HIDN*CH + 255)/256, 256, 0, stream>>>(f1w, w1b, HIDN*CH);
    k_cvt     <<<(HIDN*CH + 255)/256, 256, 0, stream>>>(f2w, w2b, CH*HIDN);
    k_outproj <<<1024, 256, 0, stream>>>(bufB, bnp, opw, opb, x, out);
    k_mlp     <<<1024, 256, 0, stream>>>(ln2w, ln2b, w1b, f1b, w2b, f2b, out);
}

// Round 3
// 370.884 us; speedup vs baseline: 4.0902x; 1.6500x over previous
//
#include <hip/hip_runtime.h>
#include <math.h>

#define CH 192
#define HW 4096
#define NB 16
#define NELEM (NB*CH*HW)
#define HIDN 768

typedef __bf16 bf16x8 __attribute__((ext_vector_type(8)));
typedef float  f32x4  __attribute__((ext_vector_type(4)));

__device__ __forceinline__ float gelu_f(float v){
    return 0.5f * v * (1.0f + erff(v * 0.70710678118654752440f));
}
__device__ __forceinline__ float sigmoid_f(float v){
    return 1.0f / (1.0f + expf(-v));
}
__device__ __forceinline__ unsigned short f2bf(float f){
    union { float f; unsigned u; } v; v.f = f;
    unsigned r = (v.u + 0x7FFFu + ((v.u >> 16) & 1u)) >> 16;
    return (unsigned short)r;
}

// ---------------- K0: f32 -> bf16 weight conversion
__global__ __launch_bounds__(256) void k_cvt(const float* __restrict__ a,
                                             unsigned short* __restrict__ o, int n){
    int i = blockIdx.x*256 + threadIdx.x;
    if (i < n) o[i] = f2bf(a[i]);
}

// ---------------- K1: LN1 + in_proj (192->384) via bf16 MFMA.
// Block = 64 pixels, 4 waves. Group 0 -> proj, group 1 -> sigmoid -> gate.
__global__ __launch_bounds__(256, 2) void k_ln_inproj(
    const float* __restrict__ x, const float* __restrict__ lw, const float* __restrict__ lb,
    const unsigned short* __restrict__ Wb, const float* __restrict__ bias,
    float* __restrict__ proj, float* __restrict__ gate)
{
    __shared__ __align__(16) float smemf[12480];   // 49920 B
    unsigned short* h2s = (unsigned short*)smemf;  // 192*64 bf16 frag-linear (24576 B)
    float* redS = smemf + 6400;
    float* redQ = redS + 256;
    float* mS   = redQ + 256;
    float* rS   = mS + 64;
    float* outb = smemf;                           // 192*65 f32 bounce (aliases h2s)

    int tid = threadIdx.x;
    int lane = tid & 63;
    int w = tid >> 6;
    int lo = lane & 15, hi = lane >> 4;
    int t = blockIdx.x;
    int b = t >> 6;
    int p0 = (t & 63) << 6;
    const float* xb = x + (size_t)b*CH*HW + p0;
    int px = lane;

    // ---- LN1: each thread covers 48 channels of one pixel
    float xv[48];
    float s = 0.f, s2 = 0.f;
    #pragma unroll
    for (int k = 0; k < 48; ++k){
        float v = xb[(size_t)(w + 4*k)*HW + px];
        xv[k] = v; s += v; s2 += v*v;
    }
    redS[tid] = s; redQ[tid] = s2;
    __syncthreads();
    if (tid < 64){
        float S = redS[tid]+redS[tid+64]+redS[tid+128]+redS[tid+192];
        float Q = redQ[tid]+redQ[tid+64]+redQ[tid+128]+redQ[tid+192];
        float mean = S * (1.f/192.f);
        float var  = Q * (1.f/192.f) - mean*mean;
        mS[tid] = mean;
        rS[tid] = rsqrtf(var + 1e-6f);
    }
    __syncthreads();
    {
        float mean = mS[px], rstd = rS[px];
        #pragma unroll
        for (int k = 0; k < 48; ++k){
            int c = w + 4*k;
            float v = (xv[k] - mean) * rstd * lw[c] + lb[c];
            int ks = c >> 5, hh = (c >> 3) & 3, j2 = c & 7;
            int idx = ((((px >> 4)*6 + ks) << 6) + hh*16 + (px & 15))*8 + j2;
            h2s[idx] = f2bf(v);
        }
    }
    __syncthreads();

    // ---- A fragments into registers
    bf16x8 afr[4][6];
    #pragma unroll
    for (int pt = 0; pt < 4; ++pt)
        #pragma unroll
        for (int ks = 0; ks < 6; ++ks)
            afr[pt][ks] = *(const bf16x8*)(const void*)(h2s + ((pt*6 + ks)*64 + lane)*8);
    __syncthreads();   // LDS free -> outb

    #pragma unroll
    for (int g = 0; g < 2; ++g){
        f32x4 acc[3][4];
        #pragma unroll
        for (int nt = 0; nt < 3; ++nt)
            #pragma unroll
            for (int pt = 0; pt < 4; ++pt)
                acc[nt][pt] = (f32x4){0.f,0.f,0.f,0.f};
        #pragma unroll
        for (int ks = 0; ks < 6; ++ks){
            #pragma unroll
            for (int nt = 0; nt < 3; ++nt){
                bf16x8 bf = *(const bf16x8*)(const void*)
                    (Wb + (size_t)(g*192 + w*48 + nt*16 + lo)*CH + ks*32 + hi*8);
                #pragma unroll
                for (int pt = 0; pt < 4; ++pt)
                    acc[nt][pt] = __builtin_amdgcn_mfma_f32_16x16x32_bf16(
                        afr[pt][ks], bf, acc[nt][pt], 0, 0, 0);
            }
        }
        #pragma unroll
        for (int nt = 0; nt < 3; ++nt){
            int ocl = w*48 + nt*16 + lo;
            #pragma unroll
            for (int pt = 0; pt < 4; ++pt)
                #pragma unroll
                for (int r = 0; r < 4; ++r)
                    outb[ocl*65 + pt*16 + hi*4 + r] = acc[nt][pt][r];
        }
        __syncthreads();
        if (g == 0){
            for (int i = tid; i < CH*64; i += 256){
                int c = i >> 6, p = i & 63;
                proj[(size_t)(b*CH + c)*HW + p0 + p] = outb[c*65 + p] + bias[c];
            }
        } else {
            for (int i = tid; i < CH*64; i += 256){
                int c = i >> 6, p = i & 63;
                gate[(size_t)(b*CH + c)*HW + p0 + p] = sigmoid_f(outb[c*65 + p] + bias[CH + c]);
            }
        }
        __syncthreads();
    }
}

// ---------------- K2: depthwise 3x3 SAME (cross-correlation)
__global__ __launch_bounds__(256) void k_dwconv(
    const float* __restrict__ in, const float* __restrict__ k9, float* __restrict__ out)
{
    __shared__ float t[66*66];
    int tid = threadIdx.x;
    int bc = blockIdx.x;
    int c = bc % CH;
    for (int i = tid; i < 66*66; i += 256) t[i] = 0.f;
    __syncthreads();
    const float* inp = in + (size_t)bc*HW;
    for (int i = tid; i < HW; i += 256){
        int y = i >> 6, xq = i & 63;
        t[(y+1)*66 + xq + 1] = inp[i];
    }
    __syncthreads();
    float kk[9];
    #pragma unroll
    for (int j = 0; j < 9; ++j) kk[j] = k9[c*9 + j];
    float* op = out + (size_t)bc*HW;
    for (int i = tid; i < HW; i += 256){
        int y = i >> 6, xq = i & 63;
        float sv = 0.f;
        #pragma unroll
        for (int dy = 0; dy < 3; ++dy)
            #pragma unroll
            for (int dx = 0; dx < 3; ++dx)
                sv = fmaf(kk[dy*3+dx], t[(y+dy)*66 + xq + dx], sv);
        op[i] = sv;
    }
}

// ---------------- K3: 4-directional EMA scans + mix, one (b,c) plane per block
__global__ __launch_bounds__(64) void k_scan(
    const float* __restrict__ pc, const float* __restrict__ dl,
    const float* __restrict__ ml, const float* __restrict__ il,
    float* __restrict__ outp)
{
    __shared__ float a[64*65];
    __shared__ float r[64*65];
    int tid = threadIdx.x;
    int bc = blockIdx.x;
    int c = bc % CH;
    float d[4], e[4], m[4], lg[4];
    float mx = -1e30f;
    #pragma unroll
    for (int k = 0; k < 4; ++k){ lg[k] = ml[k*CH + c]; mx = fmaxf(mx, lg[k]); }
    float se = 0.f;
    #pragma unroll
    for (int k = 0; k < 4; ++k){ lg[k] = expf(lg[k]-mx); se += lg[k]; }
    #pragma unroll
    for (int k = 0; k < 4; ++k){
        m[k] = lg[k] / se;
        float dd = sigmoid_f(dl[k*CH + c]);
        dd = fminf(fmaxf(dd, 0.05f), 0.995f);
        d[k] = dd;
        float is = 1.0f + tanhf(il[k*CH + c]);
        e[k] = (1.0f - dd) * is;
    }
    const float* inp = pc + (size_t)bc*HW;
    for (int i = tid; i < HW; i += 64)
        a[(i>>6)*65 + (i&63)] = inp[i];
    __syncthreads();
    {   // horizontal scans: thread = row
        float s = 0.f;
        const int base = tid*65;
        for (int xq = 0; xq < 64; ++xq){
            s = fmaf(d[0], s, e[0]*a[base+xq]);
            r[base+xq] = m[0]*s;
        }
        s = 0.f;
        for (int xq = 63; xq >= 0; --xq){
            s = fmaf(d[1], s, e[1]*a[base+xq]);
            r[base+xq] += m[1]*s;
        }
    }
    __syncthreads();
    {   // vertical scans: thread = column
        float s = 0.f;
        for (int y = 0; y < 64; ++y){
            s = fmaf(d[2], s, e[2]*a[y*65+tid]);
            r[y*65+tid] += m[2]*s;
        }
        s = 0.f;
        for (int y = 63; y >= 0; --y){
            s = fmaf(d[3], s, e[3]*a[y*65+tid]);
            r[y*65+tid] += m[3]*s;
        }
    }
    __syncthreads();
    float* op = outp + (size_t)bc*HW;
    for (int i = tid; i < HW; i += 64)
        op[i] = r[(i>>6)*65 + (i&63)];
}

// ---------------- K4: local 3x3 conv + mix + gate + BN partial stats
__global__ __launch_bounds__(256) void k_local_mix(
    const float* __restrict__ pc, const float* __restrict__ k9,
    const float* __restrict__ scn, const float* gate,
    float* mixed, float* __restrict__ part)
{
    __shared__ float t[66*66];
    __shared__ float rs[256], rq[256];
    int tid = threadIdx.x;
    int bc = blockIdx.x;
    int c = bc % CH;
    for (int i = tid; i < 66*66; i += 256) t[i] = 0.f;
    __syncthreads();
    const float* inp = pc + (size_t)bc*HW;
    for (int i = tid; i < HW; i += 256){
        int y = i >> 6, xq = i & 63;
        t[(y+1)*66 + xq + 1] = inp[i];
    }
    __syncthreads();
    float kk[9];
    #pragma unroll
    for (int j = 0; j < 9; ++j) kk[j] = k9[c*9 + j];
    float s1 = 0.f, s2 = 0.f;
    const float* sp = scn + (size_t)bc*HW;
    const float* gp = gate + (size_t)bc*HW;
    float* mp = mixed + (size_t)bc*HW;
    for (int i = tid; i < HW; i += 256){
        int y = i >> 6, xq = i & 63;
        float sv = 0.f;
        #pragma unroll
        for (int dy = 0; dy < 3; ++dy)
            #pragma unroll
            for (int dx = 0; dx < 3; ++dx)
                sv = fmaf(kk[dy*3+dx], t[(y+dy)*66 + xq + dx], sv);
        float mv = (sp[i] + sv) * gp[i];
        mp[i] = mv;
        s1 += mv; s2 += mv*mv;
    }
    rs[tid] = s1; rq[tid] = s2;
    __syncthreads();
    for (int off = 128; off > 0; off >>= 1){
        if (tid < off){ rs[tid] += rs[tid+off]; rq[tid] += rq[tid+off]; }
        __syncthreads();
    }
    if (tid == 0){ part[bc] = rs[0]; part[NB*CH + bc] = rq[0]; }
}

// ---------------- K4b: finalize BN scale/shift per channel (deterministic)
__global__ __launch_bounds__(192) void k_bn_final(
    const float* __restrict__ part, const float* __restrict__ bw,
    const float* __restrict__ bb, float* __restrict__ bnp)
{
    int c = threadIdx.x;
    float S = 0.f, Q = 0.f;
    for (int b = 0; b < NB; ++b){
        S += part[b*CH + c];
        Q += part[NB*CH + b*CH + c];
    }
    float mean = S * (1.f/65536.f);
    float var  = Q * (1.f/65536.f) - mean*mean;
    float sc = bw[c] * rsqrtf(var + 1e-5f);
    bnp[c] = sc;
    bnp[CH + c] = bb[c] - mean * sc;
}

// ---------------- K5: BN+GELU + out_proj (192->192) via bf16 MFMA + residual -> d_out
__global__ __launch_bounds__(256, 2) void k_outproj(
    const float* __restrict__ mixed, const float* __restrict__ bnp,
    const unsigned short* __restrict__ Wb, const float* __restrict__ bias,
    const float* __restrict__ x, float* __restrict__ xr)
{
    __shared__ __align__(16) float smemf[12480];   // 49920 B
    unsigned short* h2s = (unsigned short*)smemf;
    float* outb = smemf;

    int tid = threadIdx.x;
    int lane = tid & 63;
    int w = tid >> 6;
    int lo = lane & 15, hi = lane >> 4;
    int t = blockIdx.x;
    int b = t >> 6;
    int p0 = (t & 63) << 6;
    const float* mb = mixed + (size_t)b*CH*HW + p0;
    int px = lane;

    // ---- BN + GELU, frag-linear stage
    #pragma unroll
    for (int k = 0; k < 48; ++k){
        int c = w + 4*k;
        float v = mb[(size_t)c*HW + px];
        v = gelu_f(fmaf(v, bnp[c], bnp[CH + c]));
        int ks = c >> 5, hh = (c >> 3) & 3, j2 = c & 7;
        int idx = ((((px >> 4)*6 + ks) << 6) + hh*16 + (px & 15))*8 + j2;
        h2s[idx] = f2bf(v);
    }
    __syncthreads();
    bf16x8 afr[4][6];
    #pragma unroll
    for (int pt = 0; pt < 4; ++pt)
        #pragma unroll
        for (int ks = 0; ks < 6; ++ks)
            afr[pt][ks] = *(const bf16x8*)(const void*)(h2s + ((pt*6 + ks)*64 + lane)*8);
    __syncthreads();

    f32x4 acc[3][4];
    #pragma unroll
    for (int nt = 0; nt < 3; ++nt)
        #pragma unroll
        for (int pt = 0; pt < 4; ++pt)
            acc[nt][pt] = (f32x4){0.f,0.f,0.f,0.f};
    #pragma unroll
    for (int ks = 0; ks < 6; ++ks){
        #pragma unroll
        for (int nt = 0; nt < 3; ++nt){
            bf16x8 bf = *(const bf16x8*)(const void*)
                (Wb + (size_t)(w*48 + nt*16 + lo)*CH + ks*32 + hi*8);
            #pragma unroll
            for (int pt = 0; pt < 4; ++pt)
                acc[nt][pt] = __builtin_amdgcn_mfma_f32_16x16x32_bf16(
                    afr[pt][ks], bf, acc[nt][pt], 0, 0, 0);
        }
    }
    #pragma unroll
    for (int nt = 0; nt < 3; ++nt){
        int ocl = w*48 + nt*16 + lo;
        #pragma unroll
        for (int pt = 0; pt < 4; ++pt)
            #pragma unroll
            for (int r = 0; r < 4; ++r)
                outb[ocl*65 + pt*16 + hi*4 + r] = acc[nt][pt][r];
    }
    __syncthreads();
    const float* xbb = x + (size_t)b*CH*HW + p0;
    float* xrb = xr + (size_t)b*CH*HW + p0;
    for (int i = tid; i < CH*64; i += 256){
        int c = i >> 6, p = i & 63;
        size_t idx = (size_t)c*HW + p;
        xrb[idx] = xbb[idx] + bias[c] + outb[c*65 + p];
    }
}

// ---------------- K6: LN2 + fc1(bf16 MFMA) + GELU + fc2(bf16 MFMA) + residual, in-place
__global__ __launch_bounds__(256, 2) void k_mlp(
    const float* __restrict__ lw, const float* __restrict__ lb,
    const unsigned short* __restrict__ w1b, const float* __restrict__ b1,
    const unsigned short* __restrict__ w2b, const float* __restrict__ b2,
    float* io)
{
    __shared__ __align__(16) float smemf[12480];
    unsigned short* h2s = (unsigned short*)smemf;
    float* redS = smemf + 6400;
    float* redQ = redS + 256;
    float* mS   = redQ + 256;
    float* rS   = mS + 64;
    unsigned short* tt = (unsigned short*)smemf;
    float* outb = smemf;

    int tid = threadIdx.x;
    int lane = tid & 63;
    int w = tid >> 6;
    int lo = lane & 15, hi = lane >> 4;
    int t = blockIdx.x;
    int b = t >> 6;
    int p0 = (t & 63) << 6;
    float* iob = io + (size_t)b*CH*HW + p0;
    int px = lane;

    float xv[48];
    float s = 0.f, s2 = 0.f;
    #pragma unroll
    for (int k = 0; k < 48; ++k){
        float v = iob[(size_t)(w + 4*k)*HW + px];
        xv[k] = v; s += v; s2 += v*v;
    }
    redS[tid] = s; redQ[tid] = s2;
    __syncthreads();
    if (tid < 64){
        float S = redS[tid]+redS[tid+64]+redS[tid+128]+redS[tid+192];
        float Q = redQ[tid]+redQ[tid+64]+redQ[tid+128]+redQ[tid+192];
        float mean = S * (1.f/192.f);
        float var  = Q * (1.f/192.f) - mean*mean;
        mS[tid] = mean;
        rS[tid] = rsqrtf(var + 1e-6f);
    }
    __syncthreads();
    {
        float mean = mS[px], rstd = rS[px];
        #pragma unroll
        for (int k = 0; k < 48; ++k){
            int c = w + 4*k;
            float v = (xv[k] - mean) * rstd * lw[c] + lb[c];
            int ks = c >> 5, hh = (c >> 3) & 3, j2 = c & 7;
            int idx = ((((px >> 4)*6 + ks) << 6) + hh*16 + (px & 15))*8 + j2;
            h2s[idx] = f2bf(v);
        }
    }
    __syncthreads();

    bf16x8 afr[4][6];
    #pragma unroll
    for (int pt = 0; pt < 4; ++pt)
        #pragma unroll
        for (int ks = 0; ks < 6; ++ks)
            afr[pt][ks] = *(const bf16x8*)(const void*)(h2s + ((pt*6 + ks)*64 + lane)*8);
    __syncthreads();

    f32x4 acc2[3][4];
    #pragma unroll
    for (int nt2 = 0; nt2 < 3; ++nt2)
        #pragma unroll
        for (int pt = 0; pt < 4; ++pt)
            acc2[nt2][pt] = (f32x4){0.f,0.f,0.f,0.f};

    for (int hc = 0; hc < 6; ++hc){
        f32x4 acc1[2][4];
        #pragma unroll
        for (int nt = 0; nt < 2; ++nt)
            #pragma unroll
            for (int pt = 0; pt < 4; ++pt)
                acc1[nt][pt] = (f32x4){0.f,0.f,0.f,0.f};
        #pragma unroll
        for (int ks = 0; ks < 6; ++ks){
            #pragma unroll
            for (int nt = 0; nt < 2; ++nt){
                bf16x8 bf = *(const bf16x8*)(const void*)
                    (w1b + (size_t)(hc*128 + w*32 + nt*16 + lo)*CH + ks*32 + hi*8);
                #pragma unroll
                for (int pt = 0; pt < 4; ++pt)
                    acc1[nt][pt] = __builtin_amdgcn_mfma_f32_16x16x32_bf16(
                        afr[pt][ks], bf, acc1[nt][pt], 0, 0, 0);
            }
        }
        #pragma unroll
        for (int nt = 0; nt < 2; ++nt){
            int hr = w*32 + nt*16 + lo;
            float bias1 = b1[hc*128 + hr];
            int ks2 = hr >> 5, hh = (hr >> 3) & 3, j2 = hr & 7;
            #pragma unroll
            for (int pt = 0; pt < 4; ++pt){
                #pragma unroll
                for (int r = 0; r < 4; ++r){
                    int ppx = pt*16 + hi*4 + r;
                    float v = gelu_f(acc1[nt][pt][r] + bias1);
                    tt[((((ppx >> 4)*4 + ks2) << 6) + hh*16 + (ppx & 15))*8 + j2] = f2bf(v);
                }
            }
        }
        __syncthreads();
        #pragma unroll
        for (int ks2 = 0; ks2 < 4; ++ks2){
            bf16x8 a2[4];
            #pragma unroll
            for (int pt = 0; pt < 4; ++pt)
                a2[pt] = *(const bf16x8*)(const void*)(tt + ((pt*4 + ks2)*64 + lane)*8);
            #pragma unroll
            for (int nt2 = 0; nt2 < 3; ++nt2){
                bf16x8 bf2 = *(const bf16x8*)(const void*)
                    (w2b + (size_t)(w*48 + nt2*16 + lo)*HIDN + hc*128 + ks2*32 + hi*8);
                #pragma unroll
                for (int pt = 0; pt < 4; ++pt)
                    acc2[nt2][pt] = __builtin_amdgcn_mfma_f32_16x16x32_bf16(
                        a2[pt], bf2, acc2[nt2][pt], 0, 0, 0);
            }
        }
        __syncthreads();
    }

    #pragma unroll
    for (int nt2 = 0; nt2 < 3; ++nt2){
        int oc = w*48 + nt2*16 + lo;
        #pragma unroll
        for (int pt = 0; pt < 4; ++pt)
            #pragma unroll
            for (int r = 0; r < 4; ++r)
                outb[oc*65 + pt*16 + hi*4 + r] = acc2[nt2][pt][r];
    }
    __syncthreads();
    for (int i = tid; i < CH*64; i += 256){
        int c = i >> 6, p = i & 63;
        size_t idx = (size_t)c*HW + p;
        iob[idx] = iob[idx] + b2[c] + outb[c*65 + p];
    }
}

extern "C" void kernel_launch(void* const* d_in, const int* in_sizes, int n_in,
                              void* d_out, int out_size, void* d_ws, size_t ws_size,
                              hipStream_t stream) {
    const float* x    = (const float*)d_in[0];
    const float* ln1w = (const float*)d_in[1];
    const float* ln1b = (const float*)d_in[2];
    const float* ipw  = (const float*)d_in[3];
    const float* ipb  = (const float*)d_in[4];
    const float* dwk  = (const float*)d_in[5];
    const float* lek  = (const float*)d_in[6];
    const float* dlg  = (const float*)d_in[7];
    const float* mlg  = (const float*)d_in[8];
    const float* isc  = (const float*)d_in[9];
    const float* bnw  = (const float*)d_in[10];
    const float* bnb  = (const float*)d_in[11];
    const float* opw  = (const float*)d_in[12];
    const float* opb  = (const float*)d_in[13];
    const float* ln2w = (const float*)d_in[14];
    const float* ln2b = (const float*)d_in[15];
    const float* f1w  = (const float*)d_in[16];
    const float* f1b  = (const float*)d_in[17];
    const float* f2w  = (const float*)d_in[18];
    const float* f2b  = (const float*)d_in[19];

    float* out  = (float*)d_out;
    float* ws   = (float*)d_ws;
    float* bufA = ws;                    // proj, then scanned
    float* bufB = ws + (size_t)NELEM;    // sigmoid(gate), then mixed (in-place)
    float* bufC = ws + (size_t)2*NELEM;  // pconv (dwconv'd projected)
    float* part = ws + (size_t)3*NELEM;  // BN partials
    float* bnp  = part + 2*NB*CH;        // BN scale/shift

    unsigned short* ipwb = (unsigned short*)(bnp + 2*CH);
    unsigned short* opwb = ipwb + (size_t)2*CH*CH;
    unsigned short* w1b  = opwb + (size_t)CH*CH;
    unsigned short* w2b  = w1b  + (size_t)HIDN*CH;

    k_cvt<<<(2*CH*CH + 255)/256, 256, 0, stream>>>(ipw, ipwb, 2*CH*CH);
    k_cvt<<<(CH*CH + 255)/256, 256, 0, stream>>>(opw, opwb, CH*CH);
    k_cvt<<<(HIDN*CH + 255)/256, 256, 0, stream>>>(f1w, w1b, HIDN*CH);
    k_cvt<<<(HIDN*CH + 255)/256, 256, 0, stream>>>(f2w, w2b, CH*HIDN);

    k_ln_inproj<<<1024, 256, 0, stream>>>(x, ln1w, ln1b, ipwb, ipb, bufA, bufB);
    k_dwconv  <<<NB*CH, 256, 0, stream>>>(bufA, dwk, bufC);
    k_scan    <<<NB*CH,  64, 0, stream>>>(bufC, dlg, mlg, isc, bufA);
    k_local_mix<<<NB*CH, 256, 0, stream>>>(bufC, lek, bufA, bufB, bufB, part);
    k_bn_final<<<1, 192, 0, stream>>>(part, bnw, bnb, bnp);
    k_outproj <<<1024, 256, 0, stream>>>(bufB, bnp, opwb, opb, x, out);
    k_mlp     <<<1024, 256, 0, stream>>>(ln2w, ln2b, w1b, f1b, w2b, f2b, out);
}

// Round 4
// 273.940 us; speedup vs baseline: 5.5376x; 1.3539x over previous
//
#include <hip/hip_runtime.h>
#include <math.h>

#define CH 192
#define HW 4096
#define NB 16
#define NELEM (NB*CH*HW)
#define HIDN 768

typedef __bf16 bf16x8 __attribute__((ext_vector_type(8)));
typedef float  f32x4  __attribute__((ext_vector_type(4)));

__device__ __forceinline__ float gelu_f(float v){
    float u = 0.7978845608f * v * (1.0f + 0.044715f*v*v);
    float t = 1.0f - 2.0f/(1.0f + __expf(2.0f*u));
    return 0.5f * v * (1.0f + t);
}
__device__ __forceinline__ float sigmoid_f(float v){
    return 1.0f / (1.0f + __expf(-v));
}
__device__ __forceinline__ float bf2f(unsigned short u){
    union { unsigned u; float f; } v; v.u = ((unsigned)u) << 16; return v.f;
}

// ---------------- K0: f32 -> bf16 weight conversion
__global__ __launch_bounds__(256) void k_cvt(const float* __restrict__ a,
                                             __bf16* __restrict__ o, int n){
    int i = blockIdx.x*256 + threadIdx.x;
    if (i < n) o[i] = (__bf16)a[i];
}

// ---------------- K1: LN1 + in_proj (192->384) via bf16 MFMA -> bf16 proj / sigmoid gate
__global__ __launch_bounds__(256, 3) void k_ln_inproj(
    const float* __restrict__ x, const float* __restrict__ lw, const float* __restrict__ lb,
    const __bf16* __restrict__ Wb, const float* __restrict__ bias,
    unsigned short* __restrict__ proj, unsigned short* __restrict__ gate)
{
    __shared__ __align__(16) unsigned char smem[24576 + 2560 + 25344];
    __bf16* h2s = (__bf16*)smem;                       // 192*64 frag-linear
    float* redS = (float*)(smem + 24576);
    float* redQ = redS + 256;
    float* mS   = redQ + 256;
    float* rS   = mS + 64;
    __bf16* outb = (__bf16*)(smem + 27136);            // 192*66 bf16 bounce

    int tid = threadIdx.x;
    int lane = tid & 63;
    int w = tid >> 6;
    int lo = lane & 15, hi = lane >> 4;
    int bid = blockIdx.x;
    int b = bid >> 6;
    int p0 = (bid & 63) << 6;
    const float* xb = x + (size_t)b*CH*HW + p0;
    int px = lane;

    // LN1: thread covers 48 contiguous channels of one pixel
    float xv[48];
    float s = 0.f, s2 = 0.f;
    #pragma unroll
    for (int k = 0; k < 48; ++k){
        float v = xb[(size_t)(48*w + k)*HW + px];
        xv[k] = v; s += v; s2 += v*v;
    }
    redS[tid] = s; redQ[tid] = s2;
    __syncthreads();
    if (tid < 64){
        float S = redS[tid]+redS[tid+64]+redS[tid+128]+redS[tid+192];
        float Q = redQ[tid]+redQ[tid+64]+redQ[tid+128]+redQ[tid+192];
        float mean = S * (1.f/192.f);
        float var  = Q * (1.f/192.f) - mean*mean;
        mS[tid] = mean;
        rS[tid] = rsqrtf(var + 1e-6f);
    }
    __syncthreads();
    {
        float mean = mS[px], rstd = rS[px];
        #pragma unroll
        for (int m = 0; m < 6; ++m){
            int c8 = 48*w + 8*m;
            int ks = c8 >> 5, hh = (c8 >> 3) & 3;
            bf16x8 pk;
            #pragma unroll
            for (int j = 0; j < 8; ++j){
                int c = c8 + j;
                pk[j] = (__bf16)((xv[8*m + j] - mean) * rstd * lw[c] + lb[c]);
            }
            *(bf16x8*)(h2s + (((px>>4)*6 + ks)*64 + hh*16 + (px & 15))*8) = pk;
        }
    }
    __syncthreads();

    #pragma unroll
    for (int g = 0; g < 2; ++g){
        f32x4 acc[3][4];
        #pragma unroll
        for (int nt = 0; nt < 3; ++nt)
            #pragma unroll
            for (int pt = 0; pt < 4; ++pt)
                acc[nt][pt] = (f32x4){0.f,0.f,0.f,0.f};
        #pragma unroll
        for (int ks = 0; ks < 6; ++ks){
            bf16x8 a[4];
            #pragma unroll
            for (int pt = 0; pt < 4; ++pt)
                a[pt] = *(const bf16x8*)(h2s + ((pt*6 + ks)*64 + lane)*8);
            #pragma unroll
            for (int nt = 0; nt < 3; ++nt){
                bf16x8 bf = *(const bf16x8*)
                    (Wb + (size_t)(g*192 + w*48 + nt*16 + lo)*CH + ks*32 + hi*8);
                #pragma unroll
                for (int pt = 0; pt < 4; ++pt)
                    acc[nt][pt] = __builtin_amdgcn_mfma_f32_16x16x32_bf16(
                        a[pt], bf, acc[nt][pt], 0, 0, 0);
            }
        }
        #pragma unroll
        for (int nt = 0; nt < 3; ++nt){
            int ocl = w*48 + nt*16 + lo;
            float bv = bias[g*CH + ocl];
            #pragma unroll
            for (int pt = 0; pt < 4; ++pt)
                #pragma unroll
                for (int r = 0; r < 4; ++r){
                    float v = acc[nt][pt][r] + bv;
                    if (g == 1) v = sigmoid_f(v);
                    outb[ocl*66 + pt*16 + hi*4 + r] = (__bf16)v;
                }
        }
        __syncthreads();
        unsigned short* dst = (g == 0) ? proj : gate;
        const unsigned short* ob = (const unsigned short*)outb;
        for (int i = tid; i < CH*64; i += 256){
            int c = i >> 6, p = i & 63;
            dst[(size_t)(b*CH + c)*HW + p0 + p] = ob[c*66 + p];
        }
        __syncthreads();
    }
}

// ---------------- K2: fused spatial: dwconv3 + 4-dir scans + local conv3 + gate + BN partials
__global__ __launch_bounds__(256, 3) void k_spatial(
    const unsigned short* __restrict__ proj, const unsigned short* __restrict__ gate,
    const float* __restrict__ dwk, const float* __restrict__ lek,
    const float* __restrict__ dl, const float* __restrict__ ml, const float* __restrict__ il,
    float* __restrict__ mixed, float* __restrict__ part)
{
    __shared__ float t[66*67];
    __shared__ float r[64*65];
    __shared__ float r2[64*65];
    __shared__ float rs[256], rq[256];
    int tid = threadIdx.x;
    int lane = tid & 63;
    int w = tid >> 6;
    int bc = blockIdx.x;
    int c = bc % CH;
    const unsigned short* pp = proj + (size_t)bc*HW;

    // load padded plane (bf16 -> f32)
    for (int i = tid; i < 66*66; i += 256){
        int yy = i / 66, xx = i - yy*66;
        float v = 0.f;
        if (yy >= 1 && yy <= 64 && xx >= 1 && xx <= 64)
            v = bf2f(pp[(yy-1)*64 + (xx-1)]);
        t[yy*67 + xx] = v;
    }
    // per-channel scan params
    float d[4], e[4], m[4];
    {
        float lg[4], mx = -1e30f;
        #pragma unroll
        for (int k = 0; k < 4; ++k){ lg[k] = ml[k*CH + c]; mx = fmaxf(mx, lg[k]); }
        float se = 0.f;
        #pragma unroll
        for (int k = 0; k < 4; ++k){ lg[k] = __expf(lg[k]-mx); se += lg[k]; }
        #pragma unroll
        for (int k = 0; k < 4; ++k){
            m[k] = lg[k] / se;
            float dd = sigmoid_f(dl[k*CH + c]);
            dd = fminf(fmaxf(dd, 0.05f), 0.995f);
            d[k] = dd;
            e[k] = (1.0f - dd) * (1.0f + tanhf(il[k*CH + c]));
        }
    }
    __syncthreads();
    // depthwise 3x3 (dw_k) into registers
    float kk[9];
    #pragma unroll
    for (int j = 0; j < 9; ++j) kk[j] = dwk[c*9 + j];
    float dw[16];
    #pragma unroll
    for (int j = 0; j < 16; ++j){
        int i = tid + j*256;
        int y = i >> 6, xx = i & 63;
        float sv = 0.f;
        #pragma unroll
        for (int dy = 0; dy < 3; ++dy)
            #pragma unroll
            for (int dx = 0; dx < 3; ++dx)
                sv = fmaf(kk[dy*3+dx], t[(y+dy)*67 + xx + dx], sv);
        dw[j] = sv;
    }
    __syncthreads();
    #pragma unroll
    for (int j = 0; j < 16; ++j){
        int i = tid + j*256;
        t[((i>>6)+1)*67 + (i & 63) + 1] = dw[j];
    }
    __syncthreads();
    // scans: phase 1 (lr -> r, tb -> r2), phase 2 (rl += r, bt += r2)
    if (w == 0){
        int y = lane; float s = 0.f;
        for (int xx = 0; xx < 64; ++xx){
            s = fmaf(d[0], s, e[0]*t[(y+1)*67 + xx + 1]);
            r[y*65 + xx] = m[0]*s;
        }
    } else if (w == 1){
        int xx = lane; float s = 0.f;
        for (int y = 0; y < 64; ++y){
            s = fmaf(d[2], s, e[2]*t[(y+1)*67 + xx + 1]);
            r2[y*65 + xx] = m[2]*s;
        }
    }
    __syncthreads();
    if (w == 2){
        int y = lane; float s = 0.f;
        for (int xx = 63; xx >= 0; --xx){
            s = fmaf(d[1], s, e[1]*t[(y+1)*67 + xx + 1]);
            r[y*65 + xx] += m[1]*s;
        }
    } else if (w == 3){
        int xx = lane; float s = 0.f;
        for (int y = 63; y >= 0; --y){
            s = fmaf(d[3], s, e[3]*t[(y+1)*67 + xx + 1]);
            r2[y*65 + xx] += m[3]*s;
        }
    }
    __syncthreads();
    // local conv (le_k) + mix + gate + BN partial stats
    float lk[9];
    #pragma unroll
    for (int j = 0; j < 9; ++j) lk[j] = lek[c*9 + j];
    const unsigned short* gp = gate + (size_t)bc*HW;
    float* mp = mixed + (size_t)bc*HW;
    float s1 = 0.f, s2 = 0.f;
    #pragma unroll
    for (int j = 0; j < 16; ++j){
        int i = tid + j*256;
        int y = i >> 6, xx = i & 63;
        float sv = 0.f;
        #pragma unroll
        for (int dy = 0; dy < 3; ++dy)
            #pragma unroll
            for (int dx = 0; dx < 3; ++dx)
                sv = fmaf(lk[dy*3+dx], t[(y+dy)*67 + xx + dx], sv);
        float mv = (r[y*65 + xx] + r2[y*65 + xx] + sv) * bf2f(gp[i]);
        mp[i] = mv;
        s1 += mv; s2 += mv*mv;
    }
    rs[tid] = s1; rq[tid] = s2;
    __syncthreads();
    for (int off = 128; off > 0; off >>= 1){
        if (tid < off){ rs[tid] += rs[tid+off]; rq[tid] += rq[tid+off]; }
        __syncthreads();
    }
    if (tid == 0){ part[bc] = rs[0]; part[NB*CH + bc] = rq[0]; }
}

// ---------------- K2b: finalize BN scale/shift per channel (deterministic)
__global__ __launch_bounds__(192) void k_bn_final(
    const float* __restrict__ part, const float* __restrict__ bw,
    const float* __restrict__ bb, float* __restrict__ bnp)
{
    int c = threadIdx.x;
    float S = 0.f, Q = 0.f;
    for (int b = 0; b < NB; ++b){
        S += part[b*CH + c];
        Q += part[NB*CH + b*CH + c];
    }
    float mean = S * (1.f/65536.f);
    float var  = Q * (1.f/65536.f) - mean*mean;
    float sc = bw[c] * rsqrtf(var + 1e-5f);
    bnp[c] = sc;
    bnp[CH + c] = bb[c] - mean * sc;
}

// ---------------- K3: BN+GELU + out_proj (192->192) MFMA + residual -> d_out
__global__ __launch_bounds__(256, 3) void k_outproj(
    const float* __restrict__ mixed, const float* __restrict__ bnp,
    const __bf16* __restrict__ Wb, const float* __restrict__ bias,
    const float* __restrict__ x, float* __restrict__ xr)
{
    __shared__ __align__(16) unsigned char smem[34304];
    __bf16* h2s = (__bf16*)smem;       // 192*64 frag-linear (24576B)
    float* outb = (float*)smem;        // bounce passes (aliases h2s after MFMA)

    int tid = threadIdx.x;
    int lane = tid & 63;
    int w = tid >> 6;
    int lo = lane & 15, hi = lane >> 4;
    int bid = blockIdx.x;
    int b = bid >> 6;
    int p0 = (bid & 63) << 6;
    const float* mb = mixed + (size_t)b*CH*HW + p0;
    int px = lane;

    // BN + GELU -> frag-linear bf16
    #pragma unroll
    for (int m = 0; m < 6; ++m){
        int c8 = 48*w + 8*m;
        int ks = c8 >> 5, hh = (c8 >> 3) & 3;
        bf16x8 pk;
        #pragma unroll
        for (int j = 0; j < 8; ++j){
            int c = c8 + j;
            float v = mb[(size_t)c*HW + px];
            pk[j] = (__bf16)gelu_f(fmaf(v, bnp[c], bnp[CH + c]));
        }
        *(bf16x8*)(h2s + (((px>>4)*6 + ks)*64 + hh*16 + (px & 15))*8) = pk;
    }
    __syncthreads();

    f32x4 acc[3][4];
    #pragma unroll
    for (int nt = 0; nt < 3; ++nt)
        #pragma unroll
        for (int pt = 0; pt < 4; ++pt)
            acc[nt][pt] = (f32x4){0.f,0.f,0.f,0.f};
    #pragma unroll
    for (int ks = 0; ks < 6; ++ks){
        bf16x8 a[4];
        #pragma unroll
        for (int pt = 0; pt < 4; ++pt)
            a[pt] = *(const bf16x8*)(h2s + ((pt*6 + ks)*64 + lane)*8);
        #pragma unroll
        for (int nt = 0; nt < 3; ++nt){
            bf16x8 bf = *(const bf16x8*)
                (Wb + (size_t)(w*48 + nt*16 + lo)*CH + ks*32 + hi*8);
            #pragma unroll
            for (int pt = 0; pt < 4; ++pt)
                acc[nt][pt] = __builtin_amdgcn_mfma_f32_16x16x32_bf16(
                    a[pt], bf, acc[nt][pt], 0, 0, 0);
        }
    }
    __syncthreads();   // h2s reads done -> outb may overwrite

    const float* xbb = x + (size_t)b*CH*HW + p0;
    float* xrb = xr + (size_t)b*CH*HW + p0;
    // pass A: nt = 0,1  (compact cc = w*32 + nt*16 + lo, 128 channels)
    #pragma unroll
    for (int nt = 0; nt < 2; ++nt){
        int cc = w*32 + nt*16 + lo;
        #pragma unroll
        for (int pt = 0; pt < 4; ++pt)
            #pragma unroll
            for (int r = 0; r < 4; ++r)
                outb[cc*67 + pt*16 + hi*4 + r] = acc[nt][pt][r];
    }
    __syncthreads();
    for (int i = tid; i < 128*64; i += 256){
        int cc = i >> 6, p = i & 63;
        int c = (cc >> 5)*48 + (cc & 31);
        size_t idx = (size_t)c*HW + p;
        xrb[idx] = xbb[idx] + bias[c] + outb[cc*67 + p];
    }
    __syncthreads();
    // pass B: nt = 2  (compact cc = w*16 + lo, 64 channels)
    {
        int cc = w*16 + lo;
        #pragma unroll
        for (int pt = 0; pt < 4; ++pt)
            #pragma unroll
            for (int r = 0; r < 4; ++r)
                outb[cc*67 + pt*16 + hi*4 + r] = acc[2][pt][r];
    }
    __syncthreads();
    for (int i = tid; i < 64*64; i += 256){
        int cc = i >> 6, p = i & 63;
        int c = (cc >> 4)*48 + 32 + (cc & 15);
        size_t idx = (size_t)c*HW + p;
        xrb[idx] = xbb[idx] + bias[c] + outb[cc*67 + p];
    }
}

// ---------------- K4: LN2 + fc1 MFMA + GELU + fc2 MFMA + residual, in-place on d_out
__global__ __launch_bounds__(256, 3) void k_mlp(
    const float* __restrict__ lw, const float* __restrict__ lb,
    const __bf16* __restrict__ w1b, const float* __restrict__ b1,
    const __bf16* __restrict__ w2b, const float* __restrict__ b2,
    float* io)
{
    __shared__ __align__(16) unsigned char smem[43520];
    __bf16* h2s = (__bf16*)smem;                   // 192*64 frag-linear, persistent
    float* redS = (float*)(smem + 24576);
    float* redQ = redS + 256;
    float* mS   = redQ + 256;
    float* rS   = mS + 64;
    __bf16* tt  = (__bf16*)(smem + 27136);         // 128*64 frag-linear (fc1 out)
    float* outb = (float*)smem;                    // bounce (aliases h2s+red after loop)

    int tid = threadIdx.x;
    int lane = tid & 63;
    int w = tid >> 6;
    int lo = lane & 15, hi = lane >> 4;
    int bid = blockIdx.x;
    int b = bid >> 6;
    int p0 = (bid & 63) << 6;
    float* iob = io + (size_t)b*CH*HW + p0;
    int px = lane;

    // LN2
    float xv[48];
    float s = 0.f, s2 = 0.f;
    #pragma unroll
    for (int k = 0; k < 48; ++k){
        float v = iob[(size_t)(48*w + k)*HW + px];
        xv[k] = v; s += v; s2 += v*v;
    }
    redS[tid] = s; redQ[tid] = s2;
    __syncthreads();
    if (tid < 64){
        float S = redS[tid]+redS[tid+64]+redS[tid+128]+redS[tid+192];
        float Q = redQ[tid]+redQ[tid+64]+redQ[tid+128]+redQ[tid+192];
        float mean = S * (1.f/192.f);
        float var  = Q * (1.f/192.f) - mean*mean;
        mS[tid] = mean;
        rS[tid] = rsqrtf(var + 1e-6f);
    }
    __syncthreads();
    {
        float mean = mS[px], rstd = rS[px];
        #pragma unroll
        for (int m = 0; m < 6; ++m){
            int c8 = 48*w + 8*m;
            int ks = c8 >> 5, hh = (c8 >> 3) & 3;
            bf16x8 pk;
            #pragma unroll
            for (int j = 0; j < 8; ++j){
                int c = c8 + j;
                pk[j] = (__bf16)((xv[8*m + j] - mean) * rstd * lw[c] + lb[c]);
            }
            *(bf16x8*)(h2s + (((px>>4)*6 + ks)*64 + hh*16 + (px & 15))*8) = pk;
        }
    }
    __syncthreads();

    f32x4 acc2[3][4];
    #pragma unroll
    for (int nt2 = 0; nt2 < 3; ++nt2)
        #pragma unroll
        for (int pt = 0; pt < 4; ++pt)
            acc2[nt2][pt] = (f32x4){0.f,0.f,0.f,0.f};

    for (int hc = 0; hc < 6; ++hc){
        f32x4 acc1[2][4];
        #pragma unroll
        for (int nt = 0; nt < 2; ++nt)
            #pragma unroll
            for (int pt = 0; pt < 4; ++pt)
                acc1[nt][pt] = (f32x4){0.f,0.f,0.f,0.f};
        #pragma unroll
        for (int ks = 0; ks < 6; ++ks){
            bf16x8 a[4];
            #pragma unroll
            for (int pt = 0; pt < 4; ++pt)
                a[pt] = *(const bf16x8*)(h2s + ((pt*6 + ks)*64 + lane)*8);
            #pragma unroll
            for (int nt = 0; nt < 2; ++nt){
                bf16x8 bf = *(const bf16x8*)
                    (w1b + (size_t)(hc*128 + w*32 + nt*16 + lo)*CH + ks*32 + hi*8);
                #pragma unroll
                for (int pt = 0; pt < 4; ++pt)
                    acc1[nt][pt] = __builtin_amdgcn_mfma_f32_16x16x32_bf16(
                        a[pt], bf, acc1[nt][pt], 0, 0, 0);
            }
        }
        #pragma unroll
        for (int nt = 0; nt < 2; ++nt){
            int hr = w*32 + nt*16 + lo;
            float b1v = b1[hc*128 + hr];
            int ks2 = hr >> 5, hh2 = (hr >> 3) & 3, j2 = hr & 7;
            #pragma unroll
            for (int pt = 0; pt < 4; ++pt)
                #pragma unroll
                for (int r = 0; r < 4; ++r){
                    int ppx = pt*16 + hi*4 + r;
                    tt[(((ppx>>4)*4 + ks2)*64 + hh2*16 + (ppx & 15))*8 + j2]
                        = (__bf16)gelu_f(acc1[nt][pt][r] + b1v);
                }
        }
        __syncthreads();
        #pragma unroll
        for (int ks2 = 0; ks2 < 4; ++ks2){
            bf16x8 a2[4];
            #pragma unroll
            for (int pt = 0; pt < 4; ++pt)
                a2[pt] = *(const bf16x8*)(tt + ((pt*4 + ks2)*64 + lane)*8);
            #pragma unroll
            for (int nt2 = 0; nt2 < 3; ++nt2){
                bf16x8 bf2 = *(const bf16x8*)
                    (w2b + (size_t)(w*48 + nt2*16 + lo)*HIDN + hc*128 + ks2*32 + hi*8);
                #pragma unroll
                for (int pt = 0; pt < 4; ++pt)
                    acc2[nt2][pt] = __builtin_amdgcn_mfma_f32_16x16x32_bf16(
                        a2[pt], bf2, acc2[nt2][pt], 0, 0, 0);
            }
        }
        __syncthreads();
    }

    // epilogue: two bounce passes, coalesced read-modify-write of io
    #pragma unroll
    for (int nt2 = 0; nt2 < 2; ++nt2){
        int cc = w*32 + nt2*16 + lo;
        #pragma unroll
        for (int pt = 0; pt < 4; ++pt)
            #pragma unroll
            for (int r = 0; r < 4; ++r)
                outb[cc*67 + pt*16 + hi*4 + r] = acc2[nt2][pt][r];
    }
    __syncthreads();
    for (int i = tid; i < 128*64; i += 256){
        int cc = i >> 6, p = i & 63;
        int c = (cc >> 5)*48 + (cc & 31);
        size_t idx = (size_t)c*HW + p;
        iob[idx] = iob[idx] + b2[c] + outb[cc*67 + p];
    }
    __syncthreads();
    {
        int cc = w*16 + lo;
        #pragma unroll
        for (int pt = 0; pt < 4; ++pt)
            #pragma unroll
            for (int r = 0; r < 4; ++r)
                outb[cc*67 + pt*16 + hi*4 + r] = acc2[2][pt][r];
    }
    __syncthreads();
    for (int i = tid; i < 64*64; i += 256){
        int cc = i >> 6, p = i & 63;
        int c = (cc >> 4)*48 + 32 + (cc & 15);
        size_t idx = (size_t)c*HW + p;
        iob[idx] = iob[idx] + b2[c] + outb[cc*67 + p];
    }
}

extern "C" void kernel_launch(void* const* d_in, const int* in_sizes, int n_in,
                              void* d_out, int out_size, void* d_ws, size_t ws_size,
                              hipStream_t stream) {
    const float* x    = (const float*)d_in[0];
    const float* ln1w = (const float*)d_in[1];
    const float* ln1b = (const float*)d_in[2];
    const float* ipw  = (const float*)d_in[3];
    const float* ipb  = (const float*)d_in[4];
    const float* dwk  = (const float*)d_in[5];
    const float* lek  = (const float*)d_in[6];
    const float* dlg  = (const float*)d_in[7];
    const float* mlg  = (const float*)d_in[8];
    const float* isc  = (const float*)d_in[9];
    const float* bnw  = (const float*)d_in[10];
    const float* bnb  = (const float*)d_in[11];
    const float* opw  = (const float*)d_in[12];
    const float* opb  = (const float*)d_in[13];
    const float* ln2w = (const float*)d_in[14];
    const float* ln2b = (const float*)d_in[15];
    const float* f1w  = (const float*)d_in[16];
    const float* f1b  = (const float*)d_in[17];
    const float* f2w  = (const float*)d_in[18];
    const float* f2b  = (const float*)d_in[19];

    float* out = (float*)d_out;
    unsigned short* bufP = (unsigned short*)d_ws;           // proj bf16
    unsigned short* bufG = bufP + (size_t)NELEM;            // gate bf16
    float* bufM = (float*)(bufG + (size_t)NELEM);           // mixed f32
    float* part = bufM + (size_t)NELEM;
    float* bnp  = part + 2*NB*CH;
    __bf16* ipwb = (__bf16*)(bnp + 2*CH);
    __bf16* opwb = ipwb + (size_t)2*CH*CH;
    __bf16* w1b  = opwb + (size_t)CH*CH;
    __bf16* w2b  = w1b  + (size_t)HIDN*CH;

    k_cvt<<<(2*CH*CH + 255)/256, 256, 0, stream>>>(ipw, ipwb, 2*CH*CH);
    k_cvt<<<(CH*CH + 255)/256, 256, 0, stream>>>(opw, opwb, CH*CH);
    k_cvt<<<(HIDN*CH + 255)/256, 256, 0, stream>>>(f1w, w1b, HIDN*CH);
    k_cvt<<<(HIDN*CH + 255)/256, 256, 0, stream>>>(f2w, w2b, CH*HIDN);

    k_ln_inproj<<<1024, 256, 0, stream>>>(x, ln1w, ln1b, ipwb, ipb, bufP, bufG);
    k_spatial  <<<NB*CH, 256, 0, stream>>>(bufP, bufG, dwk, lek, dlg, mlg, isc, bufM, part);
    k_bn_final <<<1, 192, 0, stream>>>(part, bnw, bnb, bnp);
    k_outproj  <<<1024, 256, 0, stream>>>(bufM, bnp, opwb, opb, x, out);
    k_mlp      <<<1024, 256, 0, stream>>>(ln2w, ln2b, w1b, f1b, w2b, f2b, out);
}